// Round 11
// baseline (225.350 us; speedup 1.0000x reference)
//
#include <hip/hip_runtime.h>

typedef _Float16 half8  __attribute__((ext_vector_type(8)));
typedef _Float16 half4v __attribute__((ext_vector_type(4)));
typedef _Float16 half2v __attribute__((ext_vector_type(2)));
typedef float    f32x4  __attribute__((ext_vector_type(4)));

__device__ __forceinline__ int swz(int row) {
    return ((row ^ (row >> 3)) & 15) << 4;   // 256B-row region, 16B granules
}

// One WG = one (b,h,n) 128x128 attention block. 8 waves; wave w owns q-rows
// [16w,16w+16) end-to-end via swapped-operand QK^T (acc = mfma(K,Q) = S^T):
// lane holds its own q-row's scores -> 2-shuffle softmax, P stays in registers
// (64-shuffle redistribution to PV B-fragments). One barrier per block.
// LDS 64KB: [0,32K) K fp16 swz; [32K,64K) Vt fp16 swz.
// R10 delta vs R9: O stores are NON-TEMPORAL (O is never re-read; keep L3
// for Q/K/V replay residency -> lower FETCH_SIZE if HBM-side is binding).
__global__ __launch_bounds__(512, 4) void battn_kernel(
    const float* __restrict__ Q, const float* __restrict__ K,
    const float* __restrict__ V, float* __restrict__ O)
{
    __shared__ __align__(16) char smem[65536];
    const int tid  = threadIdx.x;
    const int lane = tid & 63;
    const int w    = tid >> 6;
    const int la   = lane & 15;
    const int u    = lane >> 4;
    const size_t base = (size_t)blockIdx.x * (128 * 128);

    const float* Qb = Q + base;
    const float* Kb = K + base;
    const float* Vb = V + base;
    float*       Ob = O + base;

    // ---------------- staging: K, V, Q loads ----------------
    float4 kreg[8];
#pragma unroll
    for (int it = 0; it < 8; ++it)
        kreg[it] = *(const float4*)(Kb + it * 2048 + tid * 4);

    float4 vreg[2][4];                              // rows j0,j0+1 x cols d0..d0+7
#pragma unroll
    for (int it = 0; it < 2; ++it) {
        const int tau = it * 512 + tid;
        const int d0 = (tau & 15) * 8;
        const int j0 = (tau >> 4) * 2;
        vreg[it][0] = *(const float4*)(Vb + j0 * 128 + d0);
        vreg[it][1] = *(const float4*)(Vb + j0 * 128 + d0 + 4);
        vreg[it][2] = *(const float4*)(Vb + (j0 + 1) * 128 + d0);
        vreg[it][3] = *(const float4*)(Vb + (j0 + 1) * 128 + d0 + 4);
    }
    half8 qfrag[4];
    {
        const float* qrow = Qb + (w * 16 + la) * 128;
#pragma unroll
        for (int kk = 0; kk < 4; ++kk) {
            const float4 a = *(const float4*)(qrow + kk * 32 + u * 8);
            const float4 b = *(const float4*)(qrow + kk * 32 + u * 8 + 4);
            qfrag[kk][0] = (_Float16)a.x; qfrag[kk][1] = (_Float16)a.y;
            qfrag[kk][2] = (_Float16)a.z; qfrag[kk][3] = (_Float16)a.w;
            qfrag[kk][4] = (_Float16)b.x; qfrag[kk][5] = (_Float16)b.y;
            qfrag[kk][6] = (_Float16)b.z; qfrag[kk][7] = (_Float16)b.w;
        }
    }
    // K -> LDS fp16 row-major swizzled
#pragma unroll
    for (int it = 0; it < 8; ++it) {
        const int idx = it * 2048 + tid * 4;
        const int row = idx >> 7;
        const int col = idx & 127;
        half4v h;
        h[0] = (_Float16)kreg[it].x; h[1] = (_Float16)kreg[it].y;
        h[2] = (_Float16)kreg[it].z; h[3] = (_Float16)kreg[it].w;
        int byte = row * 256 + col * 2;
        byte ^= swz(row);
        *(half4v*)(smem + byte) = h;
    }
    // V -> LDS transposed (Vt[d][j]) swizzled
#pragma unroll
    for (int it = 0; it < 2; ++it) {
        const int tau = it * 512 + tid;
        const int d0 = (tau & 15) * 8;
        const int j0 = (tau >> 4) * 2;
        const float r0[8] = {vreg[it][0].x, vreg[it][0].y, vreg[it][0].z, vreg[it][0].w,
                             vreg[it][1].x, vreg[it][1].y, vreg[it][1].z, vreg[it][1].w};
        const float r1[8] = {vreg[it][2].x, vreg[it][2].y, vreg[it][2].z, vreg[it][2].w,
                             vreg[it][3].x, vreg[it][3].y, vreg[it][3].z, vreg[it][3].w};
#pragma unroll
        for (int i = 0; i < 8; ++i) {
            half2v h;
            h[0] = (_Float16)r0[i];
            h[1] = (_Float16)r1[i];
            const int row = d0 + i;                 // Vt row = d
            int byte = 32768 + row * 256 + j0 * 2;
            byte ^= swz(row);
            *(half2v*)(smem + byte) = h;
        }
    }
    __syncthreads();                                // the ONLY barrier

    // ---------------- S^T = K Q^T : A=K rows, B=Q ----------------
    // acc[jt][r] = S[q = 16w+la][j = 16jt + 4u + r]  (lane owns its q-row)
    f32x4 acc[8];
#pragma unroll
    for (int t = 0; t < 8; ++t) acc[t] = (f32x4){0.f, 0.f, 0.f, 0.f};
#pragma unroll
    for (int t = 0; t < 8; ++t) {
#pragma unroll
        for (int kk = 0; kk < 4; ++kk) {
            const int row = t * 16 + la;            // K row = j
            int byte = row * 256 + kk * 64 + u * 16;
            byte ^= swz(row);
            const half8 kf = *(const half8*)(smem + byte);
            acc[t] = __builtin_amdgcn_mfma_f32_16x16x32_f16(kf, qfrag[kk], acc[t], 0, 0, 0);
        }
    }

    // ---------------- softmax: in-lane over 32 + cross-u (2 shuffles) ----------------
    float m = acc[0][0];
#pragma unroll
    for (int t = 0; t < 8; ++t)
#pragma unroll
        for (int r = 0; r < 4; ++r) m = fmaxf(m, acc[t][r]);
    m = fmaxf(m, __shfl_xor(m, 16));
    m = fmaxf(m, __shfl_xor(m, 32));
    float s = 0.f;
#pragma unroll
    for (int t = 0; t < 8; ++t)
#pragma unroll
        for (int r = 0; r < 4; ++r) {
            const float e = __expf(acc[t][r] - m);
            acc[t][r] = e;
            s += e;
        }
    s += __shfl_xor(s, 16);
    s += __shfl_xor(s, 32);
    const float inv = 1.0f / s;
#pragma unroll
    for (int t = 0; t < 8; ++t)
#pragma unroll
        for (int r = 0; r < 4; ++r) acc[t][r] *= inv;

    // ---------------- in-register P redistribution -> PV B-fragments ----------------
    // pa[kk][i] = P[q][32kk + 8u + i]; source lane = la + 32(u&1) + 16(i>>2),
    // source reg = acc[2kk + (u>>1)][i&3]   (all sent indices compile-time).
    const int srcA = la + 32 * (u & 1);
    const int srcB = srcA + 16;
    const int hi   = u >> 1;
    half8 pa[4];
#pragma unroll
    for (int kk = 0; kk < 4; ++kk) {
#pragma unroll
        for (int r = 0; r < 4; ++r) {
            const float sA0 = __shfl(acc[2 * kk][r],     srcA);
            const float sA1 = __shfl(acc[2 * kk + 1][r], srcA);
            const float sB0 = __shfl(acc[2 * kk][r],     srcB);
            const float sB1 = __shfl(acc[2 * kk + 1][r], srcB);
            pa[kk][r]     = (_Float16)(hi ? sA1 : sA0);
            pa[kk][4 + r] = (_Float16)(hi ? sB1 : sB0);
        }
    }

    // ---------------- O^T = Vt * P^T : A = Vt rows (m=d), B = pa (n=q) ----------------
#pragma unroll
    for (int dt = 0; dt < 8; ++dt) {
        f32x4 oa = (f32x4){0.f, 0.f, 0.f, 0.f};
#pragma unroll
        for (int kk = 0; kk < 4; ++kk) {
            const int row = dt * 16 + la;           // Vt row = d
            int byte = 32768 + row * 256 + kk * 64 + u * 16;
            byte ^= swz(row);
            const half8 vf = *(const half8*)(smem + byte);
            oa = __builtin_amdgcn_mfma_f32_16x16x32_f16(vf, pa[kk], oa, 0, 0, 0);
        }
        // lane holds O[q = 16w+la][d = dt*16 + 4u + r] -> contiguous float4
        // NON-TEMPORAL via ext_vector type (HIP_vector_type rejected by builtin).
        f32x4* dst = (f32x4*)(Ob + (w * 16 + la) * 128 + dt * 16 + u * 4);
        __builtin_nontemporal_store(oa, dst);
    }
}

extern "C" void kernel_launch(void* const* d_in, const int* in_sizes, int n_in,
                              void* d_out, int out_size, void* d_ws, size_t ws_size,
                              hipStream_t stream) {
    const float* q = (const float*)d_in[0];
    const float* k = (const float*)d_in[1];
    const float* v = (const float*)d_in[2];
    float* o = (float*)d_out;
    const int nblocks = in_sizes[0] / (128 * 128);   // 4096
    battn_kernel<<<dim3(nblocks), dim3(512), 0, stream>>>(q, k, v, o);
}

// Round 12
// 211.949 us; speedup vs baseline: 1.0632x; 1.0632x over previous
//
#include <hip/hip_runtime.h>

typedef _Float16 half8  __attribute__((ext_vector_type(8)));
typedef _Float16 half4v __attribute__((ext_vector_type(4)));
typedef _Float16 half2v __attribute__((ext_vector_type(2)));
typedef float    f32x4  __attribute__((ext_vector_type(4)));

__device__ __forceinline__ int swz(int row) {
    return ((row ^ (row >> 3)) & 15) << 4;   // 256B-row region, 16B granules
}

// One WG = one (b,h,n) 128x128 attention block. 8 waves; wave w owns q-rows
// [16w,16w+16) end-to-end via swapped-operand QK^T (acc = mfma(K,Q) = S^T):
// lane holds its own q-row's scores -> 2-shuffle softmax, P stays in registers
// (64-shuffle redistribution to PV B-fragments). One barrier per block.
// LDS 64KB: [0,32K) K fp16 swz; [32K,64K) Vt fp16 swz.
// FINAL (R9 revert): demand-BW-bound at ~5.1 TB/s combined demand (81% of the
// 6.29 TB/s pure-copy ceiling); 11 structural variants all land 209-225 us.
__global__ __launch_bounds__(512, 4) void battn_kernel(
    const float* __restrict__ Q, const float* __restrict__ K,
    const float* __restrict__ V, float* __restrict__ O)
{
    __shared__ __align__(16) char smem[65536];
    const int tid  = threadIdx.x;
    const int lane = tid & 63;
    const int w    = tid >> 6;
    const int la   = lane & 15;
    const int u    = lane >> 4;
    const size_t base = (size_t)blockIdx.x * (128 * 128);

    const float* Qb = Q + base;
    const float* Kb = K + base;
    const float* Vb = V + base;
    float*       Ob = O + base;

    // ---------------- staging: K, V, Q loads ----------------
    float4 kreg[8];
#pragma unroll
    for (int it = 0; it < 8; ++it)
        kreg[it] = *(const float4*)(Kb + it * 2048 + tid * 4);

    float4 vreg[2][4];                              // rows j0,j0+1 x cols d0..d0+7
#pragma unroll
    for (int it = 0; it < 2; ++it) {
        const int tau = it * 512 + tid;
        const int d0 = (tau & 15) * 8;
        const int j0 = (tau >> 4) * 2;
        vreg[it][0] = *(const float4*)(Vb + j0 * 128 + d0);
        vreg[it][1] = *(const float4*)(Vb + j0 * 128 + d0 + 4);
        vreg[it][2] = *(const float4*)(Vb + (j0 + 1) * 128 + d0);
        vreg[it][3] = *(const float4*)(Vb + (j0 + 1) * 128 + d0 + 4);
    }
    half8 qfrag[4];
    {
        const float* qrow = Qb + (w * 16 + la) * 128;
#pragma unroll
        for (int kk = 0; kk < 4; ++kk) {
            const float4 a = *(const float4*)(qrow + kk * 32 + u * 8);
            const float4 b = *(const float4*)(qrow + kk * 32 + u * 8 + 4);
            qfrag[kk][0] = (_Float16)a.x; qfrag[kk][1] = (_Float16)a.y;
            qfrag[kk][2] = (_Float16)a.z; qfrag[kk][3] = (_Float16)a.w;
            qfrag[kk][4] = (_Float16)b.x; qfrag[kk][5] = (_Float16)b.y;
            qfrag[kk][6] = (_Float16)b.z; qfrag[kk][7] = (_Float16)b.w;
        }
    }
    // K -> LDS fp16 row-major swizzled
#pragma unroll
    for (int it = 0; it < 8; ++it) {
        const int idx = it * 2048 + tid * 4;
        const int row = idx >> 7;
        const int col = idx & 127;
        half4v h;
        h[0] = (_Float16)kreg[it].x; h[1] = (_Float16)kreg[it].y;
        h[2] = (_Float16)kreg[it].z; h[3] = (_Float16)kreg[it].w;
        int byte = row * 256 + col * 2;
        byte ^= swz(row);
        *(half4v*)(smem + byte) = h;
    }
    // V -> LDS transposed (Vt[d][j]) swizzled
#pragma unroll
    for (int it = 0; it < 2; ++it) {
        const int tau = it * 512 + tid;
        const int d0 = (tau & 15) * 8;
        const int j0 = (tau >> 4) * 2;
        const float r0[8] = {vreg[it][0].x, vreg[it][0].y, vreg[it][0].z, vreg[it][0].w,
                             vreg[it][1].x, vreg[it][1].y, vreg[it][1].z, vreg[it][1].w};
        const float r1[8] = {vreg[it][2].x, vreg[it][2].y, vreg[it][2].z, vreg[it][2].w,
                             vreg[it][3].x, vreg[it][3].y, vreg[it][3].z, vreg[it][3].w};
#pragma unroll
        for (int i = 0; i < 8; ++i) {
            half2v h;
            h[0] = (_Float16)r0[i];
            h[1] = (_Float16)r1[i];
            const int row = d0 + i;                 // Vt row = d
            int byte = 32768 + row * 256 + j0 * 2;
            byte ^= swz(row);
            *(half2v*)(smem + byte) = h;
        }
    }
    __syncthreads();                                // the ONLY barrier

    // ---------------- S^T = K Q^T : A=K rows, B=Q ----------------
    // acc[jt][r] = S[q = 16w+la][j = 16jt + 4u + r]  (lane owns its q-row)
    f32x4 acc[8];
#pragma unroll
    for (int t = 0; t < 8; ++t) acc[t] = (f32x4){0.f, 0.f, 0.f, 0.f};
#pragma unroll
    for (int t = 0; t < 8; ++t) {
#pragma unroll
        for (int kk = 0; kk < 4; ++kk) {
            const int row = t * 16 + la;            // K row = j
            int byte = row * 256 + kk * 64 + u * 16;
            byte ^= swz(row);
            const half8 kf = *(const half8*)(smem + byte);
            acc[t] = __builtin_amdgcn_mfma_f32_16x16x32_f16(kf, qfrag[kk], acc[t], 0, 0, 0);
        }
    }

    // ---------------- softmax: in-lane over 32 + cross-u (2 shuffles) ----------------
    float m = acc[0][0];
#pragma unroll
    for (int t = 0; t < 8; ++t)
#pragma unroll
        for (int r = 0; r < 4; ++r) m = fmaxf(m, acc[t][r]);
    m = fmaxf(m, __shfl_xor(m, 16));
    m = fmaxf(m, __shfl_xor(m, 32));
    float s = 0.f;
#pragma unroll
    for (int t = 0; t < 8; ++t)
#pragma unroll
        for (int r = 0; r < 4; ++r) {
            const float e = __expf(acc[t][r] - m);
            acc[t][r] = e;
            s += e;
        }
    s += __shfl_xor(s, 16);
    s += __shfl_xor(s, 32);
    const float inv = 1.0f / s;
#pragma unroll
    for (int t = 0; t < 8; ++t)
#pragma unroll
        for (int r = 0; r < 4; ++r) acc[t][r] *= inv;

    // ---------------- in-register P redistribution -> PV B-fragments ----------------
    // pa[kk][i] = P[q][32kk + 8u + i]; source lane = la + 32(u&1) + 16(i>>2),
    // source reg = acc[2kk + (u>>1)][i&3]   (all sent indices compile-time).
    const int srcA = la + 32 * (u & 1);
    const int srcB = srcA + 16;
    const int hi   = u >> 1;
    half8 pa[4];
#pragma unroll
    for (int kk = 0; kk < 4; ++kk) {
#pragma unroll
        for (int r = 0; r < 4; ++r) {
            const float sA0 = __shfl(acc[2 * kk][r],     srcA);
            const float sA1 = __shfl(acc[2 * kk + 1][r], srcA);
            const float sB0 = __shfl(acc[2 * kk][r],     srcB);
            const float sB1 = __shfl(acc[2 * kk + 1][r], srcB);
            pa[kk][r]     = (_Float16)(hi ? sA1 : sA0);
            pa[kk][4 + r] = (_Float16)(hi ? sB1 : sB0);
        }
    }

    // ---------------- O^T = Vt * P^T : A = Vt rows (m=d), B = pa (n=q) ----------------
#pragma unroll
    for (int dt = 0; dt < 8; ++dt) {
        f32x4 oa = (f32x4){0.f, 0.f, 0.f, 0.f};
#pragma unroll
        for (int kk = 0; kk < 4; ++kk) {
            const int row = dt * 16 + la;           // Vt row = d
            int byte = 32768 + row * 256 + kk * 64 + u * 16;
            byte ^= swz(row);
            const half8 vf = *(const half8*)(smem + byte);
            oa = __builtin_amdgcn_mfma_f32_16x16x32_f16(vf, pa[kk], oa, 0, 0, 0);
        }
        // lane holds O[q = 16w+la][d = dt*16 + 4u + r] -> contiguous float4
        *(float4*)(Ob + (w * 16 + la) * 128 + dt * 16 + u * 4) =
            make_float4(oa[0], oa[1], oa[2], oa[3]);
    }
}

extern "C" void kernel_launch(void* const* d_in, const int* in_sizes, int n_in,
                              void* d_out, int out_size, void* d_ws, size_t ws_size,
                              hipStream_t stream) {
    const float* q = (const float*)d_in[0];
    const float* k = (const float*)d_in[1];
    const float* v = (const float*)d_in[2];
    float* o = (float*)d_out;
    const int nblocks = in_sizes[0] / (128 * 128);   // 4096
    battn_kernel<<<dim3(nblocks), dim3(512), 0, stream>>>(q, k, v, o);
}